// Round 2
// baseline (233.193 us; speedup 1.0000x reference)
//
#include <hip/hip_runtime.h>
#include <hip/hip_bf16.h>

// Problem constants (B=4, C=256, H=W=64, N=4096, G=32, DQK=32)
#define NB 4
#define CD 256
#define NT 4096
#define DQ 32

typedef __attribute__((ext_vector_type(8))) __bf16 bf16x8;
typedef __attribute__((ext_vector_type(16))) float float16v;
typedef __attribute__((ext_vector_type(4))) unsigned int uint4v;
typedef __attribute__((ext_vector_type(2))) unsigned int uint2v;

#if __has_builtin(__builtin_amdgcn_exp2f)
#define EXP2(x) __builtin_amdgcn_exp2f(x)
#else
#define EXP2(x) exp2f(x)
#endif

__device__ inline unsigned short f2bf(float f) {
  unsigned u = __float_as_uint(f);
  u += 0x7fffu + ((u >> 16) & 1u);
  return (unsigned short)(u >> 16);
}

// ---------------------------------------------------------------------------
// Prep: GroupNorm partial sums (blocks 0..511, slot writes) + weight packing
// (blocks 512..1089). scale2 = log2(e)/sqrt(32) folded into wq/bq.
// ---------------------------------------------------------------------------
__global__ __launch_bounds__(256) void gn_prep(
    const float* __restrict__ x, float* __restrict__ accum,
    const float* __restrict__ wq, const float* __restrict__ wk,
    const float* __restrict__ wv, const float* __restrict__ wp,
    const float* __restrict__ bq, const float* __restrict__ bk,
    const float* __restrict__ bv, unsigned short* __restrict__ wqkv,
    unsigned short* __restrict__ wpb, float* __restrict__ bias) {
  int bx = blockIdx.x;
  int tid = threadIdx.x;
  if (bx < 512) {
    int bg = bx >> 2, ch = bx & 3;
    const float4* xp = (const float4*)(x + (size_t)bg * 32768 + ch * 8192);
    float s = 0.f, ss = 0.f;
#pragma unroll
    for (int i = 0; i < 8; i++) {
      float4 v = xp[tid + 256 * i];
      s += v.x + v.y + v.z + v.w;
      ss += v.x * v.x + v.y * v.y + v.z * v.z + v.w * v.w;
    }
    int wid = tid >> 6, lane = tid & 63;
#pragma unroll
    for (int off = 32; off >= 1; off >>= 1) {
      s += __shfl_xor(s, off);
      ss += __shfl_xor(ss, off);
    }
    __shared__ float red[8];
    if (lane == 0) { red[wid] = s; red[4 + wid] = ss; }
    __syncthreads();
    if (tid == 0) {
      accum[2 * bx] = red[0] + red[1] + red[2] + red[3];
      accum[2 * bx + 1] = red[4] + red[5] + red[6] + red[7];
    }
  } else {
    const float scale2 = 0.2550348909867343f;  // log2(e)/sqrt(32)
    int i = (bx - 512) * 256 + tid;
    if (i < 320 * 256) {
      int j = i >> 8, c = i & 255;
      float v;
      if (j < 32) v = wq[j * 256 + c] * scale2;
      else if (j < 64) v = wk[(j - 32) * 256 + c];
      else v = wv[(j - 64) * 256 + c];
      wqkv[i] = f2bf(v);
    } else if (i < 320 * 256 + 256 * 256) {
      int k = i - 320 * 256;
      wpb[k] = f2bf(wp[k]);
    } else if (i < 320 * 256 + 256 * 256 + 320) {
      int j = i - (320 * 256 + 256 * 256);
      float v;
      if (j < 32) v = bq[j] * scale2;
      else if (j < 64) v = bk[j - 32];
      else v = bv[j - 64];
      bias[j] = v;
    }
  }
}

// ---------------------------------------------------------------------------
// GroupNorm apply; combines the 4 chunk partials, writes h[B][N][C] bf16.
// ---------------------------------------------------------------------------
__global__ __launch_bounds__(256) void gn_apply(
    const float* __restrict__ x, const float* __restrict__ gamma,
    const float* __restrict__ beta, const float* __restrict__ accum,
    unsigned short* __restrict__ h) {
  int bg = blockIdx.x >> 2, nc = blockIdx.x & 3;
  int tid = threadIdx.x;
  float S = accum[8 * bg] + accum[8 * bg + 2] + accum[8 * bg + 4] +
            accum[8 * bg + 6];
  float SS = accum[8 * bg + 1] + accum[8 * bg + 3] + accum[8 * bg + 5] +
             accum[8 * bg + 7];
  float mu = S * (1.f / 32768.f);
  float var = SS * (1.f / 32768.f) - mu * mu;
  float rstd = rsqrtf(var + 1e-5f);
  int b = bg >> 5, g = bg & 31, c0 = g * 8;
  float gam[8], bet[8];
#pragma unroll
  for (int j = 0; j < 8; j++) { gam[j] = gamma[c0 + j]; bet[j] = beta[c0 + j]; }
  const float* xb = x + (size_t)bg * 32768;
#pragma unroll
  for (int i = 0; i < 4; i++) {
    int n = nc * 1024 + tid + 256 * i;
    unsigned short hv[8];
#pragma unroll
    for (int j = 0; j < 8; j++) {
      float y = (xb[j * NT + n] - mu) * rstd * gam[j] + bet[j];
      hv[j] = f2bf(y);
    }
    *(uint4v*)(h + ((size_t)(b * NT + n) * CD + c0)) = *(uint4v*)hv;
  }
}

// ---------------------------------------------------------------------------
// QKV GEMM — zero LDS, zero barriers. R7: V is written in a fragment-major
// packed layout vpk[b][itg][et][sp][lane][8] (itg = m>>6, et = e>>5,
// sp = (m>>4)&3, lane = ((m>>3)&1)*32 + (e&31), elem = m&7) so attn's PV
// B-fragments are single coalesced 1KB global loads (V never touches LDS).
// ---------------------------------------------------------------------------
__global__ __launch_bounds__(256) void qkv_gemm(
    const unsigned short* __restrict__ A, const unsigned short* __restrict__ H,
    const float* __restrict__ bias, unsigned short* __restrict__ qk,
    unsigned short* __restrict__ v) {
  int nt = blockIdx.x, mt = blockIdx.y, b = blockIdx.z;
  int tid = threadIdx.x, lane = tid & 63;
  int w = tid >> 6, mi = w & 1, ni = w >> 1;
  int l31 = lane & 31, hh = lane >> 5;
  int m_base = mt * 64 + 32 * mi;
  int n_base = nt * 128 + 64 * ni;
  const unsigned short* Arow = A + (size_t)(m_base + l31) * 256 + 8 * hh;
  const unsigned short* Hb = H + (size_t)b * NT * CD;
  const unsigned short* h0 = Hb + (size_t)(n_base + l31) * CD + 8 * hh;
  const unsigned short* h1 = h0 + (size_t)32 * CD;
  float16v acc0, acc1;
#pragma unroll
  for (int r = 0; r < 16; r++) { acc0[r] = 0.f; acc1[r] = 0.f; }
#pragma unroll
  for (int s = 0; s < 16; s++) {
    bf16x8 af = *(const bf16x8*)(Arow + 16 * s);
    bf16x8 b0 = *(const bf16x8*)(h0 + 16 * s);
    bf16x8 b1 = *(const bf16x8*)(h1 + 16 * s);
    acc0 = __builtin_amdgcn_mfma_f32_32x32x16_bf16(af, b0, acc0, 0, 0, 0);
    acc1 = __builtin_amdgcn_mfma_f32_32x32x16_bf16(af, b1, acc1, 0, 0, 0);
  }
  float bj[16];
  int jr[16];
#pragma unroll
  for (int r = 0; r < 16; r++) {
    jr[r] = m_base + (r & 3) + 8 * (r >> 2) + 4 * hh;
    bj[r] = bias[jr[r]];
  }
#pragma unroll
  for (int half = 0; half < 2; half++) {
    int n = n_base + 32 * half + l31;
#pragma unroll
    for (int r = 0; r < 16; r++) {
      float val = (half ? acc1[r] : acc0[r]) + bj[r];
      int j = jr[r];
      if (j < 64) {
        qk[((size_t)b * NT + n) * 64 + j] = f2bf(val);
      } else {
        int e = j - 64;
        int itg = n >> 6, sp = (n >> 4) & 3;
        int ls = ((n >> 3) & 1) * 32 + (e & 31);
        int el = n & 7, et = e >> 5;
        v[((((size_t)b * 64 + itg) * 8 + et) * 4 + sp) * 512 + ls * 8 + el] =
            f2bf(val);
      }
    }
  }
}

// ---------------------------------------------------------------------------
// Fused attention R7. Evidence: XCD pin cut FETCH 3.5x but dur unchanged —
// kernel is LDS-throughput-bound (~75% LDS busy: V stage writes + Vs reads
// were 94% of LDS cycles). Fix: V never touches LDS. PV B-fragments are
// coalesced 1KB global loads from packed vpk (L2-resident per XCD after the
// (b,kh)=blockIdx%8 pin). Register blocking: 8 waves = (grp=et-pair 0..3,
// km=m-half 0..1); each wave accumulates 2qi x 2et tiles over its half of
// the sp range -> each V fragment read ONCE per block (32KB/iter = tile
// size). km pairs merge f32 partials at the end via LDS (reuses dead
// Ks/Pbuf space). QK^T unchanged on waves 0..3; K staged by waves 4..7.
// LDS 64KB (2 blocks/CU); acc 64 VGPR -> ~110 total (4 waves/SIMD ok).
// ---------------------------------------------------------------------------
__global__ __launch_bounds__(512, 4) void attn_fused(
    const unsigned short* __restrict__ qk, const unsigned short* __restrict__ Vp,
    unsigned short* __restrict__ Pa, unsigned short* __restrict__ Pb,
    float* __restrict__ lp4) {
  int L = blockIdx.x;
  int xv = L & 7;          // XCD id (mod-8 round-robin)
  int b = xv >> 1;         // batch pinned to XCD pair-group
  int kh = xv & 1;         // key half pinned to XCD
  int n0 = (L >> 3) * 64;  // q-tile base
  int tid = threadIdx.x, lane = tid & 63, w = tid >> 6;
  int l31 = lane & 31, hh = lane >> 5;
  // QK^T roles (waves 0..3): quadrant (qs = q-half, ks2 = key-half-of-64)
  int qs = w & 1, ks2 = (w >> 1) & 1;
  // PV roles: grp = et-pair (0..3), km = m-half (0..1)
  int km = w & 1, grp = w >> 1;

  __shared__ __align__(16) char smem[65536];
  unsigned short* Ks = (unsigned short*)smem;              // 64x36 = 4608 B
  unsigned short* Pbuf = (unsigned short*)(smem + 4608);   // 2x32x68 = 8704 B
  float* red = (float*)smem;  // 64KB, reused for km-merge after final barrier

  const unsigned short* qkb = qk + (size_t)b * NT * 64;
  // packed V base for this (b,kh): itg = kh*32 + it, stride 16384 shorts/itg
  const unsigned short* vit = Vp + ((size_t)b * 64 + kh * 32) * 16384;

  // Q fragments (B-operand: lane&31 = q-row, k = d) — used by waves 0..3
  int n_g = n0 + 32 * qs + l31;
  bf16x8 qfr[2];
  qfr[0] = *(const bf16x8*)&qkb[(size_t)n_g * 64 + 8 * hh];
  qfr[1] = *(const bf16x8*)&qkb[(size_t)n_g * 64 + 8 * hh + 16];

  // K staging by waves 4..7 (tid>=256): row skr (0..63), 8-wide d col
  int tK = tid - 256;
  int skr = tK >> 2, skc = (tK & 3) * 8;
  int mbase = kh * 2048;
  uint4v kreg;
  if (tid >= 256)
    kreg = *(const uint4v*)&qkb[(size_t)(mbase + skr) * 64 + 32 + skc];

  float16v acc[2][2];  // [qi][et2]
#pragma unroll
  for (int q2 = 0; q2 < 2; q2++)
#pragma unroll
    for (int e2 = 0; e2 < 2; e2++)
#pragma unroll
      for (int r = 0; r < 16; r++) acc[q2][e2][r] = 0.f;
  float lsum = 0.f;
  unsigned short* Prow = &Pbuf[(qs * 32 + l31) * 68];

  for (int it = 0; it < 32; it++) {
    // V fragments for this iteration: 4 coalesced 1KB loads (et2 x spL),
    // consumed after barrier2 — latency hides under K-stage + QK^T.
    const unsigned short* vp0 =
        vit + (size_t)it * 16384 + (grp * 8 + 2 * km) * 512 + lane * 8;
    bf16x8 vf00 = *(const bf16x8*)(vp0);           // et2=0, spL=0
    bf16x8 vf01 = *(const bf16x8*)(vp0 + 512);     // et2=0, spL=1
    bf16x8 vf10 = *(const bf16x8*)(vp0 + 2048);    // et2=1, spL=0
    bf16x8 vf11 = *(const bf16x8*)(vp0 + 2560);    // et2=1, spL=1

    // stage K(it); prefetch K(it+1) — waves 4..7
    if (tid >= 256) {
      *(uint4v*)&Ks[skr * 36 + skc] = kreg;
      if (it + 1 < 32) {
        int m1 = mbase + (it + 1) * 64;
        kreg = *(const uint4v*)&qkb[(size_t)(m1 + skr) * 64 + 32 + skc];
      }
    }
    __syncthreads();  // barrier1: Ks ready; prev-iter Pbuf reads done

    if (w < 4) {
      // S^T quadrant: keys [32ks2,+32) x q-rows [32qs,+32)
      float16v st;
#pragma unroll
      for (int r = 0; r < 16; r++) st[r] = 0.f;
#pragma unroll
      for (int s = 0; s < 2; s++) {
        bf16x8 af = *(const bf16x8*)&Ks[(32 * ks2 + l31) * 36 + 16 * s + 8 * hh];
        st = __builtin_amdgcn_mfma_f32_32x32x16_bf16(af, qfr[s], st, 0, 0, 0);
      }
      // exp2 + pack pairs + write shared P rows (key cols 32ks2..+31)
#pragma unroll
      for (int rq = 0; rq < 4; rq++) {
        float e0 = EXP2(st[4 * rq + 0]);
        float e1 = EXP2(st[4 * rq + 1]);
        float e2 = EXP2(st[4 * rq + 2]);
        float e3 = EXP2(st[4 * rq + 3]);
        lsum += (e0 + e1) + (e2 + e3);
        uint2v pw;
        pw[0] = __builtin_amdgcn_perm(__float_as_uint(e1), __float_as_uint(e0),
                                      0x07060302u);
        pw[1] = __builtin_amdgcn_perm(__float_as_uint(e3), __float_as_uint(e2),
                                      0x07060302u);
        *(uint2v*)&Prow[8 * rq + 4 * hh + 32 * ks2] = pw;
      }
    }
    __syncthreads();  // barrier2: Pbuf ready

    // PV: each wave 4 MFMA per spL (2 A-frags x 2 B-frags), sp = 2km+spL
#pragma unroll
    for (int spL = 0; spL < 2; spL++) {
      int sp = 2 * km + spL;
      bf16x8 a0 = *(const bf16x8*)&Pbuf[(l31)*68 + 16 * sp + 8 * hh];
      bf16x8 a1 = *(const bf16x8*)&Pbuf[(32 + l31) * 68 + 16 * sp + 8 * hh];
      bf16x8 b0 = spL ? vf01 : vf00;
      bf16x8 b1 = spL ? vf11 : vf10;
      acc[0][0] = __builtin_amdgcn_mfma_f32_32x32x16_bf16(a0, b0, acc[0][0], 0, 0, 0);
      acc[1][0] = __builtin_amdgcn_mfma_f32_32x32x16_bf16(a1, b0, acc[1][0], 0, 0, 0);
      acc[0][1] = __builtin_amdgcn_mfma_f32_32x32x16_bf16(a0, b1, acc[0][1], 0, 0, 0);
      acc[1][1] = __builtin_amdgcn_mfma_f32_32x32x16_bf16(a1, b1, acc[1][1], 0, 0, 0);
    }
  }

  // l partials: wave (qs,ks2) holds keys 32ks2 range; combine hh halves
  if (w < 4) {
    lsum += __shfl_xor(lsum, 32);
    if (hh == 0) {
      lp4[(size_t)((kh * 2 + ks2) * NB + b) * NT + n0 + 32 * qs + l31] = lsum;
    }
  }

  // km-merge: exchange other-qi partials via LDS (Ks/Pbuf dead now)
  __syncthreads();
  if (km == 0) {
#pragma unroll
    for (int e2 = 0; e2 < 2; e2++)
#pragma unroll
      for (int r = 0; r < 16; r++)
        red[(w * 2 + e2) * 1024 + r * 64 + lane] = acc[1][e2][r];
  } else {
#pragma unroll
    for (int e2 = 0; e2 < 2; e2++)
#pragma unroll
      for (int r = 0; r < 16; r++)
        red[(w * 2 + e2) * 1024 + r * 64 + lane] = acc[0][e2][r];
  }
  __syncthreads();
  int pw = w ^ 1;
  if (km == 0) {
#pragma unroll
    for (int e2 = 0; e2 < 2; e2++)
#pragma unroll
      for (int r = 0; r < 16; r++)
        acc[0][e2][r] += red[(pw * 2 + e2) * 1024 + r * 64 + lane];
  } else {
#pragma unroll
    for (int e2 = 0; e2 < 2; e2++)
#pragma unroll
      for (int r = 0; r < 16; r++)
        acc[1][e2][r] += red[(pw * 2 + e2) * 1024 + r * 64 + lane];
  }

  // unnormalized partial O for tiles (qi=km, et = 2grp+et2)
  unsigned short* Pout = (kh ? Pb : Pa) + (size_t)b * NT * CD;
  if (km == 0) {
#pragma unroll
    for (int r = 0; r < 16; r++) {
      int nl = (r & 3) + 8 * (r >> 2) + 4 * hh;
      size_t row = (size_t)(n0 + nl) * CD + l31;
#pragma unroll
      for (int e2 = 0; e2 < 2; e2++)
        Pout[row + 32 * (2 * grp + e2)] = f2bf(acc[0][e2][r]);
    }
  } else {
#pragma unroll
    for (int r = 0; r < 16; r++) {
      int nl = (r & 3) + 8 * (r >> 2) + 4 * hh;
      size_t row = (size_t)(n0 + 32 + nl) * CD + l31;
#pragma unroll
      for (int e2 = 0; e2 < 2; e2++)
        Pout[row + 32 * (2 * grp + e2)] = f2bf(acc[1][e2][r]);
    }
  }
}

// ---------------------------------------------------------------------------
// Proj GEMM + partial-combine + bias + residual (unchanged).
// ---------------------------------------------------------------------------
__device__ inline bf16x8 combine_frag(const unsigned short* p0,
                                      const unsigned short* p1, float inv) {
  uint4v ua = *(const uint4v*)p0;
  uint4v ub = *(const uint4v*)p1;
  uint4v r;
#pragma unroll
  for (int j = 0; j < 4; j++) {
    float lo = __uint_as_float(ua[j] << 16) + __uint_as_float(ub[j] << 16);
    float hi = __uint_as_float(ua[j] & 0xffff0000u) +
               __uint_as_float(ub[j] & 0xffff0000u);
    lo *= inv;
    hi *= inv;
    r[j] = __builtin_amdgcn_perm(__float_as_uint(hi), __float_as_uint(lo),
                                 0x07060302u);
  }
  return *(bf16x8*)&r;
}

__global__ __launch_bounds__(256) void proj_gemm(
    const unsigned short* __restrict__ Wp, const unsigned short* __restrict__ Pa,
    const unsigned short* __restrict__ Pb, const float* __restrict__ lp4,
    const float* __restrict__ bp, const float* __restrict__ x,
    float* __restrict__ out) {
  int nt = blockIdx.x, mt = blockIdx.y, b = blockIdx.z;
  int tid = threadIdx.x, lane = tid & 63;
  int w = tid >> 6, mi = w & 1, ni = w >> 1;
  int l31 = lane & 31, hh = lane >> 5;
  int m_base = mt * 64 + 32 * mi;
  int n_base = nt * 128 + 64 * ni;
  const unsigned short* Arow = Wp + (size_t)(m_base + l31) * 256 + 8 * hh;
  int nA = n_base + l31, nB = nA + 32;
  float lA = 0.f, lB = 0.f;
#pragma unroll
  for (int s4 = 0; s4 < 4; s4++) {
    lA += lp4[(size_t)(s4 * NB + b) * NT + nA];
    lB += lp4[(size_t)(s4 * NB + b) * NT + nB];
  }
  float invA = 1.f / lA, invB = 1.f / lB;
  const unsigned short* a0 = Pa + ((size_t)b * NT + nA) * CD + 8 * hh;
  const unsigned short* a1 = Pa + ((size_t)b * NT + nB) * CD + 8 * hh;
  const unsigned short* c0 = Pb + ((size_t)b * NT + nA) * CD + 8 * hh;
  const unsigned short* c1 = Pb + ((size_t)b * NT + nB) * CD + 8 * hh;
  float16v acc0, acc1;
#pragma unroll
  for (int r = 0; r < 16; r++) { acc0[r] = 0.f; acc1[r] = 0.f; }
#pragma unroll
  for (int s = 0; s < 16; s++) {
    bf16x8 af = *(const bf16x8*)(Arow + 16 * s);
    bf16x8 b0 = combine_frag(a0 + 16 * s, c0 + 16 * s, invA);
    bf16x8 b1 = combine_frag(a1 + 16 * s, c1 + 16 * s, invB);
    acc0 = __builtin_amdgcn_mfma_f32_32x32x16_bf16(af, b0, acc0, 0, 0, 0);
    acc1 = __builtin_amdgcn_mfma_f32_32x32x16_bf16(af, b1, acc1, 0, 0, 0);
  }
#pragma unroll
  for (int half = 0; half < 2; half++) {
    int n = n_base + 32 * half + l31;
#pragma unroll
    for (int r = 0; r < 16; r++) {
      int f = m_base + (r & 3) + 8 * (r >> 2) + 4 * hh;
      size_t idx = ((size_t)b * CD + f) * NT + n;
      out[idx] = x[idx] + (half ? acc1[r] : acc0[r]) + bp[f];
    }
  }
}

extern "C" void kernel_launch(void* const* d_in, const int* in_sizes, int n_in,
                              void* d_out, int out_size, void* d_ws,
                              size_t ws_size, hipStream_t stream) {
  (void)in_sizes; (void)n_in; (void)out_size; (void)ws_size;
  const float* x = (const float*)d_in[0];
  const float* gamma = (const float*)d_in[1];
  const float* beta = (const float*)d_in[2];
  const float* wq = (const float*)d_in[3];
  const float* bq = (const float*)d_in[4];
  const float* wk = (const float*)d_in[5];
  const float* bk = (const float*)d_in[6];
  const float* wv = (const float*)d_in[7];
  const float* bv = (const float*)d_in[8];
  const float* wp = (const float*)d_in[9];
  const float* bp = (const float*)d_in[10];
  float* out = (float*)d_out;

  char* ws = (char*)d_ws;
  unsigned short* h_ws = (unsigned short*)ws;               // 8 MB (reused: Pa)
  unsigned short* qk_ws = (unsigned short*)(ws + 8388608);  // 2 MB
  unsigned short* v_ws = (unsigned short*)(ws + 10485760);  // 8 MB (packed V)
  unsigned short* o_ws = (unsigned short*)(ws + 18874368);  // 8 MB (Pb)
  unsigned short* wqkv_b = (unsigned short*)(ws + 27262976);  // 160 KB
  unsigned short* wp_b = (unsigned short*)(ws + 27426816);    // 128 KB
  float* bias_q = (float*)(ws + 27557888);                    // 1.25 KB
  float* accum = (float*)(ws + 27559168);                     // 4 KB
  float* lp4 = (float*)(ws + 27563264);                       // 256 KB

  gn_prep<<<1090, 256, 0, stream>>>(x, accum, wq, wk, wv, wp, bq, bk, bv,
                                    wqkv_b, wp_b, bias_q);
  gn_apply<<<512, 256, 0, stream>>>(x, gamma, beta, accum, h_ws);
  dim3 gq(32, 5, NB);
  qkv_gemm<<<gq, 256, 0, stream>>>(wqkv_b, h_ws, bias_q, qk_ws, v_ws);
  attn_fused<<<512, 512, 0, stream>>>(qk_ws, v_ws, h_ws, o_ws, lp4);
  dim3 gp(32, 4, NB);
  proj_gemm<<<gp, 256, 0, stream>>>(wp_b, h_ws, o_ws, lp4, bp, x, out);
}

// Round 3
// 186.110 us; speedup vs baseline: 1.2530x; 1.2530x over previous
//
#include <hip/hip_runtime.h>
#include <hip/hip_bf16.h>

// Problem constants (B=4, C=256, H=W=64, N=4096, G=32, DQK=32)
#define NB 4
#define CD 256
#define NT 4096
#define DQ 32

typedef __attribute__((ext_vector_type(8))) __bf16 bf16x8;
typedef __attribute__((ext_vector_type(16))) float float16v;
typedef __attribute__((ext_vector_type(4))) unsigned int uint4v;
typedef __attribute__((ext_vector_type(2))) unsigned int uint2v;

#if __has_builtin(__builtin_amdgcn_exp2f)
#define EXP2(x) __builtin_amdgcn_exp2f(x)
#else
#define EXP2(x) exp2f(x)
#endif

__device__ inline unsigned short f2bf(float f) {
  unsigned u = __float_as_uint(f);
  u += 0x7fffu + ((u >> 16) & 1u);
  return (unsigned short)(u >> 16);
}

// Raw barrier: LDS ordering only. Global loads into registers stay IN FLIGHT
// across it (the compiler's __syncthreads() would force vmcnt(0) drain — that
// drain was R7's 99us: V-load latency serialized on the critical path).
#define BARRIER() asm volatile("s_waitcnt lgkmcnt(0)\n\ts_barrier" ::: "memory")

// ---------------------------------------------------------------------------
// Prep: GroupNorm partial sums (blocks 0..511, slot writes) + weight packing
// (blocks 512..1089). scale2 = log2(e)/sqrt(32) folded into wq/bq.
// ---------------------------------------------------------------------------
__global__ __launch_bounds__(256) void gn_prep(
    const float* __restrict__ x, float* __restrict__ accum,
    const float* __restrict__ wq, const float* __restrict__ wk,
    const float* __restrict__ wv, const float* __restrict__ wp,
    const float* __restrict__ bq, const float* __restrict__ bk,
    const float* __restrict__ bv, unsigned short* __restrict__ wqkv,
    unsigned short* __restrict__ wpb, float* __restrict__ bias) {
  int bx = blockIdx.x;
  int tid = threadIdx.x;
  if (bx < 512) {
    int bg = bx >> 2, ch = bx & 3;
    const float4* xp = (const float4*)(x + (size_t)bg * 32768 + ch * 8192);
    float s = 0.f, ss = 0.f;
#pragma unroll
    for (int i = 0; i < 8; i++) {
      float4 v = xp[tid + 256 * i];
      s += v.x + v.y + v.z + v.w;
      ss += v.x * v.x + v.y * v.y + v.z * v.z + v.w * v.w;
    }
    int wid = tid >> 6, lane = tid & 63;
#pragma unroll
    for (int off = 32; off >= 1; off >>= 1) {
      s += __shfl_xor(s, off);
      ss += __shfl_xor(ss, off);
    }
    __shared__ float red[8];
    if (lane == 0) { red[wid] = s; red[4 + wid] = ss; }
    __syncthreads();
    if (tid == 0) {
      accum[2 * bx] = red[0] + red[1] + red[2] + red[3];
      accum[2 * bx + 1] = red[4] + red[5] + red[6] + red[7];
    }
  } else {
    const float scale2 = 0.2550348909867343f;  // log2(e)/sqrt(32)
    int i = (bx - 512) * 256 + tid;
    if (i < 320 * 256) {
      int j = i >> 8, c = i & 255;
      float v;
      if (j < 32) v = wq[j * 256 + c] * scale2;
      else if (j < 64) v = wk[(j - 32) * 256 + c];
      else v = wv[(j - 64) * 256 + c];
      wqkv[i] = f2bf(v);
    } else if (i < 320 * 256 + 256 * 256) {
      int k = i - 320 * 256;
      wpb[k] = f2bf(wp[k]);
    } else if (i < 320 * 256 + 256 * 256 + 320) {
      int j = i - (320 * 256 + 256 * 256);
      float v;
      if (j < 32) v = bq[j] * scale2;
      else if (j < 64) v = bk[j - 32];
      else v = bv[j - 64];
      bias[j] = v;
    }
  }
}

// ---------------------------------------------------------------------------
// GroupNorm apply; combines the 4 chunk partials, writes h[B][N][C] bf16.
// ---------------------------------------------------------------------------
__global__ __launch_bounds__(256) void gn_apply(
    const float* __restrict__ x, const float* __restrict__ gamma,
    const float* __restrict__ beta, const float* __restrict__ accum,
    unsigned short* __restrict__ h) {
  int bg = blockIdx.x >> 2, nc = blockIdx.x & 3;
  int tid = threadIdx.x;
  float S = accum[8 * bg] + accum[8 * bg + 2] + accum[8 * bg + 4] +
            accum[8 * bg + 6];
  float SS = accum[8 * bg + 1] + accum[8 * bg + 3] + accum[8 * bg + 5] +
             accum[8 * bg + 7];
  float mu = S * (1.f / 32768.f);
  float var = SS * (1.f / 32768.f) - mu * mu;
  float rstd = rsqrtf(var + 1e-5f);
  int b = bg >> 5, g = bg & 31, c0 = g * 8;
  float gam[8], bet[8];
#pragma unroll
  for (int j = 0; j < 8; j++) { gam[j] = gamma[c0 + j]; bet[j] = beta[c0 + j]; }
  const float* xb = x + (size_t)bg * 32768;
#pragma unroll
  for (int i = 0; i < 4; i++) {
    int n = nc * 1024 + tid + 256 * i;
    unsigned short hv[8];
#pragma unroll
    for (int j = 0; j < 8; j++) {
      float y = (xb[j * NT + n] - mu) * rstd * gam[j] + bet[j];
      hv[j] = f2bf(y);
    }
    *(uint4v*)(h + ((size_t)(b * NT + n) * CD + c0)) = *(uint4v*)hv;
  }
}

// ---------------------------------------------------------------------------
// QKV GEMM — zero LDS, zero barriers. V written in fragment-major packed
// layout vpk[b][itg][et][sp][lane][8] (itg = m>>6, et = e>>5, sp = (m>>4)&3,
// lane = ((m>>3)&1)*32 + (e&31), elem = m&7) so attn's PV B-fragments are
// single coalesced 1KB global loads (V never touches LDS).
// ---------------------------------------------------------------------------
__global__ __launch_bounds__(256) void qkv_gemm(
    const unsigned short* __restrict__ A, const unsigned short* __restrict__ H,
    const float* __restrict__ bias, unsigned short* __restrict__ qk,
    unsigned short* __restrict__ v) {
  int nt = blockIdx.x, mt = blockIdx.y, b = blockIdx.z;
  int tid = threadIdx.x, lane = tid & 63;
  int w = tid >> 6, mi = w & 1, ni = w >> 1;
  int l31 = lane & 31, hh = lane >> 5;
  int m_base = mt * 64 + 32 * mi;
  int n_base = nt * 128 + 64 * ni;
  const unsigned short* Arow = A + (size_t)(m_base + l31) * 256 + 8 * hh;
  const unsigned short* Hb = H + (size_t)b * NT * CD;
  const unsigned short* h0 = Hb + (size_t)(n_base + l31) * CD + 8 * hh;
  const unsigned short* h1 = h0 + (size_t)32 * CD;
  float16v acc0, acc1;
#pragma unroll
  for (int r = 0; r < 16; r++) { acc0[r] = 0.f; acc1[r] = 0.f; }
#pragma unroll
  for (int s = 0; s < 16; s++) {
    bf16x8 af = *(const bf16x8*)(Arow + 16 * s);
    bf16x8 b0 = *(const bf16x8*)(h0 + 16 * s);
    bf16x8 b1 = *(const bf16x8*)(h1 + 16 * s);
    acc0 = __builtin_amdgcn_mfma_f32_32x32x16_bf16(af, b0, acc0, 0, 0, 0);
    acc1 = __builtin_amdgcn_mfma_f32_32x32x16_bf16(af, b1, acc1, 0, 0, 0);
  }
  float bj[16];
  int jr[16];
#pragma unroll
  for (int r = 0; r < 16; r++) {
    jr[r] = m_base + (r & 3) + 8 * (r >> 2) + 4 * hh;
    bj[r] = bias[jr[r]];
  }
#pragma unroll
  for (int half = 0; half < 2; half++) {
    int n = n_base + 32 * half + l31;
#pragma unroll
    for (int r = 0; r < 16; r++) {
      float val = (half ? acc1[r] : acc0[r]) + bj[r];
      int j = jr[r];
      if (j < 64) {
        qk[((size_t)b * NT + n) * 64 + j] = f2bf(val);
      } else {
        int e = j - 64;
        int itg = n >> 6, sp = (n >> 4) & 3;
        int ls = ((n >> 3) & 1) * 32 + (e & 31);
        int el = n & 7, et = e >> 5;
        v[((((size_t)b * 64 + itg) * 8 + et) * 4 + sp) * 512 + ls * 8 + el] =
            f2bf(val);
      }
    }
  }
}

// ---------------------------------------------------------------------------
// Fused attention R8. R7 evidence: removing V from LDS made it WORSE (99us,
// MfmaUtil 15.6) because __syncthreads() forces vmcnt(0) drain — V L2 latency
// was serialized at barrier1 every iteration. R8: raw s_barrier with
// lgkmcnt-only waits (global loads stay in flight across barriers), ONE
// barrier per K-tile, everything staged one phase ahead:
//   phase p: [w4-7] write Ks[(p+1)&1] (loaded at p-1), issue K(p+2);
//            [w0-3] QK(p) from Ks[p&1] -> Pbuf[p&1];
//            [all]  PV(p-1) from Pbuf[(p-1)&1] with V(p-1) reg frags;
//            [all]  issue V(p+1) frags (full phase of flight); BARRIER.
// PV wave split: wave w = e-tile w (4 sp, both q-halves) -> no km merge,
// acc 32 f32, V dbuf 32 VGPR (~114 total, fits 128 @ 2 blocks/CU),
// LDS 26.6KB. QK(p) and PV(p-1) co-schedule inside one barrier pair.
// ---------------------------------------------------------------------------
#define K_STAGE(PCUR)                                                         \
  if (tid >= 256) {                                                           \
    *(uint4v*)&Ks[(((PCUR) + 1) & 1) * 2304 + skr * 36 + skc] = kreg;         \
    int pk_ = (PCUR) + 2 <= 31 ? (PCUR) + 2 : 31;                             \
    kreg =                                                                    \
        *(const uint4v*)&qkb[(size_t)(mbase + pk_ * 64 + skr) * 64 + 32 + skc]; \
  }

#define QK_STEP(PCUR)                                                         \
  if (w < 4) {                                                                \
    float16v st;                                                              \
    _Pragma("unroll") for (int r = 0; r < 16; r++) st[r] = 0.f;               \
    _Pragma("unroll") for (int s = 0; s < 2; s++) {                           \
      bf16x8 af = *(const bf16x8*)&Ks[((PCUR) & 1) * 2304 +                   \
                                      (32 * ks2 + l31) * 36 + 16 * s + 8 * hh]; \
      st = __builtin_amdgcn_mfma_f32_32x32x16_bf16(af, qfr[s], st, 0, 0, 0);  \
    }                                                                         \
    _Pragma("unroll") for (int rq = 0; rq < 4; rq++) {                        \
      float e0 = EXP2(st[4 * rq + 0]);                                        \
      float e1 = EXP2(st[4 * rq + 1]);                                        \
      float e2 = EXP2(st[4 * rq + 2]);                                        \
      float e3 = EXP2(st[4 * rq + 3]);                                        \
      lsum += (e0 + e1) + (e2 + e3);                                          \
      uint2v pw;                                                              \
      pw[0] = __builtin_amdgcn_perm(__float_as_uint(e1), __float_as_uint(e0), \
                                    0x07060302u);                             \
      pw[1] = __builtin_amdgcn_perm(__float_as_uint(e3), __float_as_uint(e2), \
                                    0x07060302u);                             \
      *(uint2v*)&Pbuf[((PCUR) & 1) * 4352 + (qs * 32 + l31) * 68 + 8 * rq +   \
                      4 * hh + 32 * ks2] = pw;                                \
    }                                                                         \
  }

#define PV_STEP(PPREV, CURV)                                                  \
  {                                                                           \
    _Pragma("unroll") for (int sp = 0; sp < 4; sp++) {                        \
      bf16x8 a0 = *(const bf16x8*)&Pbuf[((PPREV) & 1) * 4352 + l31 * 68 +     \
                                        16 * sp + 8 * hh];                    \
      bf16x8 a1 = *(const bf16x8*)&Pbuf[((PPREV) & 1) * 4352 +                \
                                        (32 + l31) * 68 + 16 * sp + 8 * hh];  \
      acc[0] = __builtin_amdgcn_mfma_f32_32x32x16_bf16(a0, CURV[sp], acc[0],  \
                                                       0, 0, 0);              \
      acc[1] = __builtin_amdgcn_mfma_f32_32x32x16_bf16(a1, CURV[sp], acc[1],  \
                                                       0, 0, 0);              \
    }                                                                         \
  }

#define V_LOAD(DST, ITX)                                                      \
  {                                                                           \
    const unsigned short* vp_ = vbase + (size_t)(ITX)*16384;                  \
    _Pragma("unroll") for (int u = 0; u < 4; u++)                             \
        DST[u] = *(const bf16x8*)(vp_ + u * 512);                             \
  }

__global__ __launch_bounds__(512, 4) void attn_fused(
    const unsigned short* __restrict__ qk, const unsigned short* __restrict__ Vp,
    unsigned short* __restrict__ Pa, unsigned short* __restrict__ Pb,
    float* __restrict__ lp4) {
  int L = blockIdx.x;
  int xv = L & 7;          // XCD id (mod-8 round-robin)
  int b = xv >> 1;         // batch pinned to XCD pair-group
  int kh = xv & 1;         // key half pinned to XCD
  int n0 = (L >> 3) * 64;  // q-tile base
  int tid = threadIdx.x, lane = tid & 63, w = tid >> 6;
  int l31 = lane & 31, hh = lane >> 5;
  int qs = w & 1, ks2 = (w >> 1) & 1;  // QK quadrant roles (waves 0..3)

  __shared__ unsigned short Ks[2 * 2304];    // 2 x 64 keys x 36 (pad)
  __shared__ unsigned short Pbuf[2 * 4352];  // 2 x [64 q][68 keys(pad)]

  const unsigned short* qkb = qk + (size_t)b * NT * 64;
  // packed V base for this (b,kh): tile it at vit + it*16384 shorts
  const unsigned short* vit = Vp + ((size_t)b * 64 + kh * 32) * 16384;
  // wave w's 4 sp-fragments of e-tile w, per-lane 16B
  const unsigned short* vbase = vit + (size_t)w * 4 * 512 + lane * 8;

  // Q fragments (B-operand: lane&31 = q-row, k = d) — waves 0..3 only
  bf16x8 qfr[2];
  if (w < 4) {
    int n_g = n0 + 32 * qs + l31;
    qfr[0] = *(const bf16x8*)&qkb[(size_t)n_g * 64 + 8 * hh];
    qfr[1] = *(const bf16x8*)&qkb[(size_t)n_g * 64 + 8 * hh + 16];
  }

  // K staging (waves 4..7): row skr (0..63), 8-wide d col
  int tK = tid - 256;
  int skr = tK >> 2, skc = (tK & 3) * 8;
  int mbase = kh * 2048;
  uint4v kreg;

  float16v acc[2];  // [q-half], e-tile = w
#pragma unroll
  for (int q2 = 0; q2 < 2; q2++)
#pragma unroll
    for (int r = 0; r < 16; r++) acc[q2][r] = 0.f;
  float lsum = 0.f;

  bf16x8 vA[4], vB[4];
  // prologue: V(0) in flight; Ks[0] staged; kreg = K(1)
  V_LOAD(vA, 0);
  if (tid >= 256) {
    kreg = *(const uint4v*)&qkb[(size_t)(mbase + skr) * 64 + 32 + skc];
    *(uint4v*)&Ks[skr * 36 + skc] = kreg;
    kreg = *(const uint4v*)&qkb[(size_t)(mbase + 64 + skr) * 64 + 32 + skc];
  }
  BARRIER();

  // phase 0 (no PV)
  K_STAGE(0);
  QK_STEP(0);
  V_LOAD(vB, 1);
  BARRIER();

  for (int p = 1; p < 31; p += 2) {
    K_STAGE(p);
    QK_STEP(p);
    PV_STEP(p - 1, vA);
    V_LOAD(vA, p + 1);
    BARRIER();
    K_STAGE(p + 1);
    QK_STEP(p + 1);
    PV_STEP(p, vB);
    V_LOAD(vB, p + 2);
    BARRIER();
  }
  // phase 31 (no K stage, no V issue)
  QK_STEP(31);
  PV_STEP(30, vA);
  BARRIER();
  // epilogue PV(31)
  PV_STEP(31, vB);

  // l partials: wave (qs,ks2) holds keys 32ks2 range; combine hh halves
  if (w < 4) {
    lsum += __shfl_xor(lsum, 32);
    if (hh == 0) {
      lp4[(size_t)((kh * 2 + ks2) * NB + b) * NT + n0 + 32 * qs + l31] = lsum;
    }
  }

  // unnormalized partial O: wave w owns e-cols [32w, 32w+32)
  unsigned short* Pout = (kh ? Pb : Pa) + (size_t)b * NT * CD;
#pragma unroll
  for (int r = 0; r < 16; r++) {
    int nl = (r & 3) + 8 * (r >> 2) + 4 * hh;
    Pout[(size_t)(n0 + nl) * CD + 32 * w + l31] = f2bf(acc[0][r]);
    Pout[(size_t)(n0 + 32 + nl) * CD + 32 * w + l31] = f2bf(acc[1][r]);
  }
}

// ---------------------------------------------------------------------------
// Proj GEMM + partial-combine + bias + residual (unchanged).
// ---------------------------------------------------------------------------
__device__ inline bf16x8 combine_frag(const unsigned short* p0,
                                      const unsigned short* p1, float inv) {
  uint4v ua = *(const uint4v*)p0;
  uint4v ub = *(const uint4v*)p1;
  uint4v r;
#pragma unroll
  for (int j = 0; j < 4; j++) {
    float lo = __uint_as_float(ua[j] << 16) + __uint_as_float(ub[j] << 16);
    float hi = __uint_as_float(ua[j] & 0xffff0000u) +
               __uint_as_float(ub[j] & 0xffff0000u);
    lo *= inv;
    hi *= inv;
    r[j] = __builtin_amdgcn_perm(__float_as_uint(hi), __float_as_uint(lo),
                                 0x07060302u);
  }
  return *(bf16x8*)&r;
}

__global__ __launch_bounds__(256) void proj_gemm(
    const unsigned short* __restrict__ Wp, const unsigned short* __restrict__ Pa,
    const unsigned short* __restrict__ Pb, const float* __restrict__ lp4,
    const float* __restrict__ bp, const float* __restrict__ x,
    float* __restrict__ out) {
  int nt = blockIdx.x, mt = blockIdx.y, b = blockIdx.z;
  int tid = threadIdx.x, lane = tid & 63;
  int w = tid >> 6, mi = w & 1, ni = w >> 1;
  int l31 = lane & 31, hh = lane >> 5;
  int m_base = mt * 64 + 32 * mi;
  int n_base = nt * 128 + 64 * ni;
  const unsigned short* Arow = Wp + (size_t)(m_base + l31) * 256 + 8 * hh;
  int nA = n_base + l31, nB = nA + 32;
  float lA = 0.f, lB = 0.f;
#pragma unroll
  for (int s4 = 0; s4 < 4; s4++) {
    lA += lp4[(size_t)(s4 * NB + b) * NT + nA];
    lB += lp4[(size_t)(s4 * NB + b) * NT + nB];
  }
  float invA = 1.f / lA, invB = 1.f / lB;
  const unsigned short* a0 = Pa + ((size_t)b * NT + nA) * CD + 8 * hh;
  const unsigned short* a1 = Pa + ((size_t)b * NT + nB) * CD + 8 * hh;
  const unsigned short* c0 = Pb + ((size_t)b * NT + nA) * CD + 8 * hh;
  const unsigned short* c1 = Pb + ((size_t)b * NT + nB) * CD + 8 * hh;
  float16v acc0, acc1;
#pragma unroll
  for (int r = 0; r < 16; r++) { acc0[r] = 0.f; acc1[r] = 0.f; }
#pragma unroll
  for (int s = 0; s < 16; s++) {
    bf16x8 af = *(const bf16x8*)(Arow + 16 * s);
    bf16x8 b0 = combine_frag(a0 + 16 * s, c0 + 16 * s, invA);
    bf16x8 b1 = combine_frag(a1 + 16 * s, c1 + 16 * s, invB);
    acc0 = __builtin_amdgcn_mfma_f32_32x32x16_bf16(af, b0, acc0, 0, 0, 0);
    acc1 = __builtin_amdgcn_mfma_f32_32x32x16_bf16(af, b1, acc1, 0, 0, 0);
  }
#pragma unroll
  for (int half = 0; half < 2; half++) {
    int n = n_base + 32 * half + l31;
#pragma unroll
    for (int r = 0; r < 16; r++) {
      int f = m_base + (r & 3) + 8 * (r >> 2) + 4 * hh;
      size_t idx = ((size_t)b * CD + f) * NT + n;
      out[idx] = x[idx] + (half ? acc1[r] : acc0[r]) + bp[f];
    }
  }
}

extern "C" void kernel_launch(void* const* d_in, const int* in_sizes, int n_in,
                              void* d_out, int out_size, void* d_ws,
                              size_t ws_size, hipStream_t stream) {
  (void)in_sizes; (void)n_in; (void)out_size; (void)ws_size;
  const float* x = (const float*)d_in[0];
  const float* gamma = (const float*)d_in[1];
  const float* beta = (const float*)d_in[2];
  const float* wq = (const float*)d_in[3];
  const float* bq = (const float*)d_in[4];
  const float* wk = (const float*)d_in[5];
  const float* bk = (const float*)d_in[6];
  const float* wv = (const float*)d_in[7];
  const float* bv = (const float*)d_in[8];
  const float* wp = (const float*)d_in[9];
  const float* bp = (const float*)d_in[10];
  float* out = (float*)d_out;

  char* ws = (char*)d_ws;
  unsigned short* h_ws = (unsigned short*)ws;               // 8 MB (reused: Pa)
  unsigned short* qk_ws = (unsigned short*)(ws + 8388608);  // 2 MB
  unsigned short* v_ws = (unsigned short*)(ws + 10485760);  // 8 MB (packed V)
  unsigned short* o_ws = (unsigned short*)(ws + 18874368);  // 8 MB (Pb)
  unsigned short* wqkv_b = (unsigned short*)(ws + 27262976);  // 160 KB
  unsigned short* wp_b = (unsigned short*)(ws + 27426816);    // 128 KB
  float* bias_q = (float*)(ws + 27557888);                    // 1.25 KB
  float* accum = (float*)(ws + 27559168);                     // 4 KB
  float* lp4 = (float*)(ws + 27563264);                       // 256 KB

  gn_prep<<<1090, 256, 0, stream>>>(x, accum, wq, wk, wv, wp, bq, bk, bv,
                                    wqkv_b, wp_b, bias_q);
  gn_apply<<<512, 256, 0, stream>>>(x, gamma, beta, accum, h_ws);
  dim3 gq(32, 5, NB);
  qkv_gemm<<<gq, 256, 0, stream>>>(wqkv_b, h_ws, bias_q, qk_ws, v_ws);
  attn_fused<<<512, 512, 0, stream>>>(qk_ws, v_ws, h_ws, o_ws, lp4);
  dim3 gp(32, 4, NB);
  proj_gemm<<<gp, 256, 0, stream>>>(wp_b, h_ws, o_ws, lp4, bp, x, out);
}

// Round 4
// 185.663 us; speedup vs baseline: 1.2560x; 1.0024x over previous
//
#include <hip/hip_runtime.h>
#include <hip/hip_bf16.h>

// Problem constants (B=4, C=256, H=W=64, N=4096, G=32, DQK=32)
#define NB 4
#define CD 256
#define NT 4096
#define DQ 32

typedef __attribute__((ext_vector_type(8))) __bf16 bf16x8;
typedef __attribute__((ext_vector_type(16))) float float16v;
typedef __attribute__((ext_vector_type(4))) unsigned int uint4v;
typedef __attribute__((ext_vector_type(2))) unsigned int uint2v;

#if __has_builtin(__builtin_amdgcn_exp2f)
#define EXP2(x) __builtin_amdgcn_exp2f(x)
#else
#define EXP2(x) exp2f(x)
#endif

__device__ inline unsigned short f2bf(float f) {
  unsigned u = __float_as_uint(f);
  u += 0x7fffu + ((u >> 16) & 1u);
  return (unsigned short)(u >> 16);
}

// Raw barrier: LDS ordering only. Global loads into registers stay IN FLIGHT
// across it (the compiler's __syncthreads() forces vmcnt(0) drain — that
// drain was R7's 99us regression).
#define BARRIER() asm volatile("s_waitcnt lgkmcnt(0)\n\ts_barrier" ::: "memory")

// ---------------------------------------------------------------------------
// Fused GroupNorm (single pass, x kept in registers) + weight packing.
// Blocks 0..127: one block per (b,g); 1024 threads; thread t holds
// x[ch=0..8][n=4t..4t+4) (32 floats) -> local sums -> LDS reduce ->
// normalize in-reg -> 4x 16B stores to h[b][n][c]. Removes the 2-kernel
// gn_prep/gn_apply split, the accum round-trip, and a full 16.8MB x re-read.
// Blocks 128..272: weight packing (scale2 = log2(e)/sqrt(32) folded in wq/bq).
// ---------------------------------------------------------------------------
__global__ __launch_bounds__(1024) void gn_fused(
    const float* __restrict__ x, const float* __restrict__ gamma,
    const float* __restrict__ beta, const float* __restrict__ wq,
    const float* __restrict__ wk, const float* __restrict__ wv,
    const float* __restrict__ wp, const float* __restrict__ bq,
    const float* __restrict__ bk, const float* __restrict__ bv,
    unsigned short* __restrict__ h, unsigned short* __restrict__ wqkv,
    unsigned short* __restrict__ wpb, float* __restrict__ bias) {
  int bx = blockIdx.x;
  int tid = threadIdx.x;
  if (bx < 128) {
    int b = bx >> 5, g = bx & 31, c0 = g * 8;
    const float4* xp = (const float4*)(x + (size_t)bx * 32768);
    float va[32];
    float s = 0.f, ss = 0.f;
#pragma unroll
    for (int i = 0; i < 8; i++) {
      float4 t4 = xp[i * 1024 + tid];
      va[4 * i + 0] = t4.x;
      va[4 * i + 1] = t4.y;
      va[4 * i + 2] = t4.z;
      va[4 * i + 3] = t4.w;
      s += t4.x + t4.y + t4.z + t4.w;
      ss += t4.x * t4.x + t4.y * t4.y + t4.z * t4.z + t4.w * t4.w;
    }
#pragma unroll
    for (int off = 32; off >= 1; off >>= 1) {
      s += __shfl_xor(s, off);
      ss += __shfl_xor(ss, off);
    }
    __shared__ float red[32];
    int wid = tid >> 6;
    if ((tid & 63) == 0) {
      red[wid] = s;
      red[16 + wid] = ss;
    }
    __syncthreads();
    float S = 0.f, SS = 0.f;
#pragma unroll
    for (int i = 0; i < 16; i++) {
      S += red[i];
      SS += red[16 + i];
    }
    float mu = S * (1.f / 32768.f);
    float rstd = rsqrtf(SS * (1.f / 32768.f) - mu * mu + 1e-5f);
    float gam[8], bet[8];
#pragma unroll
    for (int i = 0; i < 8; i++) {
      gam[i] = gamma[c0 + i] * rstd;
      bet[i] = beta[c0 + i] - mu * gamma[c0 + i] * rstd;
    }
    unsigned short* hb = h + (size_t)b * NT * CD + c0;
#pragma unroll
    for (int j = 0; j < 4; j++) {
      unsigned short hv[8];
#pragma unroll
      for (int i = 0; i < 8; i++) {
        hv[i] = f2bf(va[4 * i + j] * gam[i] + bet[i]);
      }
      *(uint4v*)(hb + (size_t)(4 * tid + j) * CD) = *(uint4v*)hv;
    }
  } else {
    const float scale2 = 0.2550348909867343f;  // log2(e)/sqrt(32)
    int i = (bx - 128) * 1024 + tid;
    if (i < 320 * 256) {
      int j = i >> 8, c = i & 255;
      float v;
      if (j < 32) v = wq[j * 256 + c] * scale2;
      else if (j < 64) v = wk[(j - 32) * 256 + c];
      else v = wv[(j - 64) * 256 + c];
      wqkv[i] = f2bf(v);
    } else if (i < 320 * 256 + 256 * 256) {
      int k = i - 320 * 256;
      wpb[k] = f2bf(wp[k]);
    } else if (i < 320 * 256 + 256 * 256 + 320) {
      int j = i - (320 * 256 + 256 * 256);
      float v;
      if (j < 32) v = bq[j] * scale2;
      else if (j < 64) v = bk[j - 32];
      else v = bv[j - 64];
      bias[j] = v;
    }
  }
}

// ---------------------------------------------------------------------------
// QKV GEMM — zero LDS, zero barriers. V written in fragment-major packed
// layout vpk[b][itg][et][sp][lane][8] (itg = m>>6, et = e>>5, sp = (m>>4)&3,
// lane = ((m>>3)&1)*32 + (e&31), elem = m&7) so attn's PV B-fragments are
// single coalesced 1KB global loads (V never touches LDS).
// ---------------------------------------------------------------------------
__global__ __launch_bounds__(256) void qkv_gemm(
    const unsigned short* __restrict__ A, const unsigned short* __restrict__ H,
    const float* __restrict__ bias, unsigned short* __restrict__ qk,
    unsigned short* __restrict__ v) {
  int nt = blockIdx.x, mt = blockIdx.y, b = blockIdx.z;
  int tid = threadIdx.x, lane = tid & 63;
  int w = tid >> 6, mi = w & 1, ni = w >> 1;
  int l31 = lane & 31, hh = lane >> 5;
  int m_base = mt * 64 + 32 * mi;
  int n_base = nt * 128 + 64 * ni;
  const unsigned short* Arow = A + (size_t)(m_base + l31) * 256 + 8 * hh;
  const unsigned short* Hb = H + (size_t)b * NT * CD;
  const unsigned short* h0 = Hb + (size_t)(n_base + l31) * CD + 8 * hh;
  const unsigned short* h1 = h0 + (size_t)32 * CD;
  float16v acc0, acc1;
#pragma unroll
  for (int r = 0; r < 16; r++) { acc0[r] = 0.f; acc1[r] = 0.f; }
#pragma unroll
  for (int s = 0; s < 16; s++) {
    bf16x8 af = *(const bf16x8*)(Arow + 16 * s);
    bf16x8 b0 = *(const bf16x8*)(h0 + 16 * s);
    bf16x8 b1 = *(const bf16x8*)(h1 + 16 * s);
    acc0 = __builtin_amdgcn_mfma_f32_32x32x16_bf16(af, b0, acc0, 0, 0, 0);
    acc1 = __builtin_amdgcn_mfma_f32_32x32x16_bf16(af, b1, acc1, 0, 0, 0);
  }
  float bj[16];
  int jr[16];
#pragma unroll
  for (int r = 0; r < 16; r++) {
    jr[r] = m_base + (r & 3) + 8 * (r >> 2) + 4 * hh;
    bj[r] = bias[jr[r]];
  }
#pragma unroll
  for (int half = 0; half < 2; half++) {
    int n = n_base + 32 * half + l31;
#pragma unroll
    for (int r = 0; r < 16; r++) {
      float val = (half ? acc1[r] : acc0[r]) + bj[r];
      int j = jr[r];
      if (j < 64) {
        qk[((size_t)b * NT + n) * 64 + j] = f2bf(val);
      } else {
        int e = j - 64;
        int itg = n >> 6, sp = (n >> 4) & 3;
        int ls = ((n >> 3) & 1) * 32 + (e & 31);
        int el = n & 7, et = e >> 5;
        v[((((size_t)b * 64 + itg) * 8 + et) * 4 + sp) * 512 + ls * 8 + el] =
            f2bf(val);
      }
    }
  }
}

// ---------------------------------------------------------------------------
// Fused attention R9 = R8 + s_setprio around MFMA clusters (T5: role-split
// schedule is the proven regime, +21-39% measured). Structure unchanged:
// raw lgkmcnt-only barriers, ONE barrier per K-tile, V register fragments
// loaded one phase ahead from packed vpk (L2-resident per XCD via the
// (b,kh)=blockIdx%8 pin), K staged by waves 4-7, QK by waves 0-3, PV by all.
// ---------------------------------------------------------------------------
#define K_STAGE(PCUR)                                                         \
  if (tid >= 256) {                                                           \
    *(uint4v*)&Ks[(((PCUR) + 1) & 1) * 2304 + skr * 36 + skc] = kreg;         \
    int pk_ = (PCUR) + 2 <= 31 ? (PCUR) + 2 : 31;                             \
    kreg =                                                                    \
        *(const uint4v*)&qkb[(size_t)(mbase + pk_ * 64 + skr) * 64 + 32 + skc]; \
  }

#define QK_STEP(PCUR)                                                         \
  if (w < 4) {                                                                \
    float16v st;                                                              \
    _Pragma("unroll") for (int r = 0; r < 16; r++) st[r] = 0.f;               \
    __builtin_amdgcn_s_setprio(1);                                            \
    _Pragma("unroll") for (int s = 0; s < 2; s++) {                           \
      bf16x8 af = *(const bf16x8*)&Ks[((PCUR) & 1) * 2304 +                   \
                                      (32 * ks2 + l31) * 36 + 16 * s + 8 * hh]; \
      st = __builtin_amdgcn_mfma_f32_32x32x16_bf16(af, qfr[s], st, 0, 0, 0);  \
    }                                                                         \
    __builtin_amdgcn_s_setprio(0);                                            \
    _Pragma("unroll") for (int rq = 0; rq < 4; rq++) {                        \
      float e0 = EXP2(st[4 * rq + 0]);                                        \
      float e1 = EXP2(st[4 * rq + 1]);                                        \
      float e2 = EXP2(st[4 * rq + 2]);                                        \
      float e3 = EXP2(st[4 * rq + 3]);                                        \
      lsum += (e0 + e1) + (e2 + e3);                                          \
      uint2v pw;                                                              \
      pw[0] = __builtin_amdgcn_perm(__float_as_uint(e1), __float_as_uint(e0), \
                                    0x07060302u);                             \
      pw[1] = __builtin_amdgcn_perm(__float_as_uint(e3), __float_as_uint(e2), \
                                    0x07060302u);                             \
      *(uint2v*)&Pbuf[((PCUR) & 1) * 4352 + (qs * 32 + l31) * 68 + 8 * rq +   \
                      4 * hh + 32 * ks2] = pw;                                \
    }                                                                         \
  }

#define PV_STEP(PPREV, CURV)                                                  \
  {                                                                           \
    __builtin_amdgcn_s_setprio(1);                                            \
    _Pragma("unroll") for (int sp = 0; sp < 4; sp++) {                        \
      bf16x8 a0 = *(const bf16x8*)&Pbuf[((PPREV) & 1) * 4352 + l31 * 68 +     \
                                        16 * sp + 8 * hh];                    \
      bf16x8 a1 = *(const bf16x8*)&Pbuf[((PPREV) & 1) * 4352 +                \
                                        (32 + l31) * 68 + 16 * sp + 8 * hh];  \
      acc[0] = __builtin_amdgcn_mfma_f32_32x32x16_bf16(a0, CURV[sp], acc[0],  \
                                                       0, 0, 0);              \
      acc[1] = __builtin_amdgcn_mfma_f32_32x32x16_bf16(a1, CURV[sp], acc[1],  \
                                                       0, 0, 0);              \
    }                                                                         \
    __builtin_amdgcn_s_setprio(0);                                            \
  }

#define V_LOAD(DST, ITX)                                                      \
  {                                                                           \
    const unsigned short* vp_ = vbase + (size_t)(ITX)*16384;                  \
    _Pragma("unroll") for (int u = 0; u < 4; u++)                             \
        DST[u] = *(const bf16x8*)(vp_ + u * 512);                             \
  }

__global__ __launch_bounds__(512, 4) void attn_fused(
    const unsigned short* __restrict__ qk, const unsigned short* __restrict__ Vp,
    unsigned short* __restrict__ Pa, unsigned short* __restrict__ Pb,
    float* __restrict__ lp4) {
  int L = blockIdx.x;
  int xv = L & 7;          // XCD id (mod-8 round-robin)
  int b = xv >> 1;         // batch pinned to XCD pair-group
  int kh = xv & 1;         // key half pinned to XCD
  int n0 = (L >> 3) * 64;  // q-tile base
  int tid = threadIdx.x, lane = tid & 63, w = tid >> 6;
  int l31 = lane & 31, hh = lane >> 5;
  int qs = w & 1, ks2 = (w >> 1) & 1;  // QK quadrant roles (waves 0..3)

  __shared__ unsigned short Ks[2 * 2304];    // 2 x 64 keys x 36 (pad)
  __shared__ unsigned short Pbuf[2 * 4352];  // 2 x [64 q][68 keys(pad)]

  const unsigned short* qkb = qk + (size_t)b * NT * 64;
  // packed V base for this (b,kh): tile it at vit + it*16384 shorts
  const unsigned short* vit = Vp + ((size_t)b * 64 + kh * 32) * 16384;
  // wave w's 4 sp-fragments of e-tile w, per-lane 16B
  const unsigned short* vbase = vit + (size_t)w * 4 * 512 + lane * 8;

  // Q fragments (B-operand: lane&31 = q-row, k = d) — waves 0..3 only
  bf16x8 qfr[2];
  if (w < 4) {
    int n_g = n0 + 32 * qs + l31;
    qfr[0] = *(const bf16x8*)&qkb[(size_t)n_g * 64 + 8 * hh];
    qfr[1] = *(const bf16x8*)&qkb[(size_t)n_g * 64 + 8 * hh + 16];
  }

  // K staging (waves 4..7): row skr (0..63), 8-wide d col
  int tK = tid - 256;
  int skr = tK >> 2, skc = (tK & 3) * 8;
  int mbase = kh * 2048;
  uint4v kreg;

  float16v acc[2];  // [q-half], e-tile = w
#pragma unroll
  for (int q2 = 0; q2 < 2; q2++)
#pragma unroll
    for (int r = 0; r < 16; r++) acc[q2][r] = 0.f;
  float lsum = 0.f;

  bf16x8 vA[4], vB[4];
  // prologue: V(0) in flight; Ks[0] staged; kreg = K(1)
  V_LOAD(vA, 0);
  if (tid >= 256) {
    kreg = *(const uint4v*)&qkb[(size_t)(mbase + skr) * 64 + 32 + skc];
    *(uint4v*)&Ks[skr * 36 + skc] = kreg;
    kreg = *(const uint4v*)&qkb[(size_t)(mbase + 64 + skr) * 64 + 32 + skc];
  }
  BARRIER();

  // phase 0 (no PV)
  K_STAGE(0);
  QK_STEP(0);
  V_LOAD(vB, 1);
  BARRIER();

  for (int p = 1; p < 31; p += 2) {
    K_STAGE(p);
    QK_STEP(p);
    PV_STEP(p - 1, vA);
    V_LOAD(vA, p + 1);
    BARRIER();
    K_STAGE(p + 1);
    QK_STEP(p + 1);
    PV_STEP(p, vB);
    V_LOAD(vB, p + 2);
    BARRIER();
  }
  // phase 31 (no K stage, no V issue)
  QK_STEP(31);
  PV_STEP(30, vA);
  BARRIER();
  // epilogue PV(31)
  PV_STEP(31, vB);

  // l partials: wave (qs,ks2) holds keys 32ks2 range; combine hh halves
  if (w < 4) {
    lsum += __shfl_xor(lsum, 32);
    if (hh == 0) {
      lp4[(size_t)((kh * 2 + ks2) * NB + b) * NT + n0 + 32 * qs + l31] = lsum;
    }
  }

  // unnormalized partial O: wave w owns e-cols [32w, 32w+32)
  unsigned short* Pout = (kh ? Pb : Pa) + (size_t)b * NT * CD;
#pragma unroll
  for (int r = 0; r < 16; r++) {
    int nl = (r & 3) + 8 * (r >> 2) + 4 * hh;
    Pout[(size_t)(n0 + nl) * CD + 32 * w + l31] = f2bf(acc[0][r]);
    Pout[(size_t)(n0 + 32 + nl) * CD + 32 * w + l31] = f2bf(acc[1][r]);
  }
}

// ---------------------------------------------------------------------------
// Proj GEMM + partial-combine + bias + residual (unchanged).
// ---------------------------------------------------------------------------
__device__ inline bf16x8 combine_frag(const unsigned short* p0,
                                      const unsigned short* p1, float inv) {
  uint4v ua = *(const uint4v*)p0;
  uint4v ub = *(const uint4v*)p1;
  uint4v r;
#pragma unroll
  for (int j = 0; j < 4; j++) {
    float lo = __uint_as_float(ua[j] << 16) + __uint_as_float(ub[j] << 16);
    float hi = __uint_as_float(ua[j] & 0xffff0000u) +
               __uint_as_float(ub[j] & 0xffff0000u);
    lo *= inv;
    hi *= inv;
    r[j] = __builtin_amdgcn_perm(__float_as_uint(hi), __float_as_uint(lo),
                                 0x07060302u);
  }
  return *(bf16x8*)&r;
}

__global__ __launch_bounds__(256) void proj_gemm(
    const unsigned short* __restrict__ Wp, const unsigned short* __restrict__ Pa,
    const unsigned short* __restrict__ Pb, const float* __restrict__ lp4,
    const float* __restrict__ bp, const float* __restrict__ x,
    float* __restrict__ out) {
  int nt = blockIdx.x, mt = blockIdx.y, b = blockIdx.z;
  int tid = threadIdx.x, lane = tid & 63;
  int w = tid >> 6, mi = w & 1, ni = w >> 1;
  int l31 = lane & 31, hh = lane >> 5;
  int m_base = mt * 64 + 32 * mi;
  int n_base = nt * 128 + 64 * ni;
  const unsigned short* Arow = Wp + (size_t)(m_base + l31) * 256 + 8 * hh;
  int nA = n_base + l31, nB = nA + 32;
  float lA = 0.f, lB = 0.f;
#pragma unroll
  for (int s4 = 0; s4 < 4; s4++) {
    lA += lp4[(size_t)(s4 * NB + b) * NT + nA];
    lB += lp4[(size_t)(s4 * NB + b) * NT + nB];
  }
  float invA = 1.f / lA, invB = 1.f / lB;
  const unsigned short* a0 = Pa + ((size_t)b * NT + nA) * CD + 8 * hh;
  const unsigned short* a1 = Pa + ((size_t)b * NT + nB) * CD + 8 * hh;
  const unsigned short* c0 = Pb + ((size_t)b * NT + nA) * CD + 8 * hh;
  const unsigned short* c1 = Pb + ((size_t)b * NT + nB) * CD + 8 * hh;
  float16v acc0, acc1;
#pragma unroll
  for (int r = 0; r < 16; r++) { acc0[r] = 0.f; acc1[r] = 0.f; }
#pragma unroll
  for (int s = 0; s < 16; s++) {
    bf16x8 af = *(const bf16x8*)(Arow + 16 * s);
    bf16x8 b0 = combine_frag(a0 + 16 * s, c0 + 16 * s, invA);
    bf16x8 b1 = combine_frag(a1 + 16 * s, c1 + 16 * s, invB);
    acc0 = __builtin_amdgcn_mfma_f32_32x32x16_bf16(af, b0, acc0, 0, 0, 0);
    acc1 = __builtin_amdgcn_mfma_f32_32x32x16_bf16(af, b1, acc1, 0, 0, 0);
  }
#pragma unroll
  for (int half = 0; half < 2; half++) {
    int n = n_base + 32 * half + l31;
#pragma unroll
    for (int r = 0; r < 16; r++) {
      int f = m_base + (r & 3) + 8 * (r >> 2) + 4 * hh;
      size_t idx = ((size_t)b * CD + f) * NT + n;
      out[idx] = x[idx] + (half ? acc1[r] : acc0[r]) + bp[f];
    }
  }
}

extern "C" void kernel_launch(void* const* d_in, const int* in_sizes, int n_in,
                              void* d_out, int out_size, void* d_ws,
                              size_t ws_size, hipStream_t stream) {
  (void)in_sizes; (void)n_in; (void)out_size; (void)ws_size;
  const float* x = (const float*)d_in[0];
  const float* gamma = (const float*)d_in[1];
  const float* beta = (const float*)d_in[2];
  const float* wq = (const float*)d_in[3];
  const float* bq = (const float*)d_in[4];
  const float* wk = (const float*)d_in[5];
  const float* bk = (const float*)d_in[6];
  const float* wv = (const float*)d_in[7];
  const float* bv = (const float*)d_in[8];
  const float* wp = (const float*)d_in[9];
  const float* bp = (const float*)d_in[10];
  float* out = (float*)d_out;

  char* ws = (char*)d_ws;
  unsigned short* h_ws = (unsigned short*)ws;               // 8 MB (reused: Pa)
  unsigned short* qk_ws = (unsigned short*)(ws + 8388608);  // 2 MB
  unsigned short* v_ws = (unsigned short*)(ws + 10485760);  // 8 MB (packed V)
  unsigned short* o_ws = (unsigned short*)(ws + 18874368);  // 8 MB (Pb)
  unsigned short* wqkv_b = (unsigned short*)(ws + 27262976);  // 160 KB
  unsigned short* wp_b = (unsigned short*)(ws + 27426816);    // 128 KB
  float* bias_q = (float*)(ws + 27557888);                    // 1.25 KB
  float* lp4 = (float*)(ws + 27563264);                       // 256 KB

  gn_fused<<<273, 1024, 0, stream>>>(x, gamma, beta, wq, wk, wv, wp, bq, bk,
                                     bv, h_ws, wqkv_b, wp_b, bias_q);
  dim3 gq(32, 5, NB);
  qkv_gemm<<<gq, 256, 0, stream>>>(wqkv_b, h_ws, bias_q, qk_ws, v_ws);
  attn_fused<<<512, 512, 0, stream>>>(qk_ws, v_ws, h_ws, o_ws, lp4);
  dim3 gp(32, 4, NB);
  proj_gemm<<<gp, 256, 0, stream>>>(wp_b, h_ws, o_ws, lp4, bp, x, out);
}